// Round 15
// baseline (1384.207 us; speedup 1.0000x reference)
//
#include <hip/hip_runtime.h>
#include <hip/hip_bf16.h>
#include <cstdint>
#include <cstddef>

// GPTQ int4 linear: out[T,N] = x[T,K] @ dequant(qweight,qzeros,scales)
// T=8192, K=4096, N=11008, GROUP=128.
// Pipeline: x->bf16, dequant->W^T[N,K] bf16, then 256x256-tile 8-wave MFMA GEMM
// (persistent, atomic tile grab).
// R15 = R12 (one-phase-ahead fragment prefetch, PROVEN-DEEP staging ledger)
//       + sched_barrier(0) pinning reads ABOVE each MFMA cluster (R13's fix,
//       which was never combined with R12's correct ledger).
// Steady phase: {GL 1 quadrant | vmcnt(4) | barrier | read NEXT quad's frags |
// SCHED0 | 16 MFMA on frags read LAST phase (already in regs, no lgkm wait)}.
// Ledger (2 loads/GL, stage order A0',B0',B1',A1' at q1..q4):
//   q1: +A0' -> vmcnt(4) drains B1(t)   [then read b1]      (3-phase slack)
//   q2: +B0' -> vmcnt(4) drains A1(t)   [then read aHi]     (3-phase slack)
//   q3: +B1' -> no wait, no barrier
//   q4: +A1' -> vmcnt(4) drains A0',B0' [then read aLo',b0'] (3-phase slack)
// Never drains to 0. Every barrier paired with its counted wait (cross-wave
// publication). WAR windows >=4 phases. Frag lifetimes (single set each):
// aLo read q4(t-1) used q1,q2; b0 read q4(t-1) used q1,q3; b1 read q1 used
// q2,q4; aHi read q2 used q3,q4.

#define K_DIM 4096
#define N_DIM 11008
#define GROUP_SZ 128
#define KB (K_DIM * 2)        // bytes per row of a K-major bf16 panel
#define NTILES_K (K_DIM / 64) // 64 K-tiles of BK=64

typedef __bf16 bf16x8_t __attribute__((ext_vector_type(8)));
typedef float f32x4_t __attribute__((ext_vector_type(4)));

__device__ __forceinline__ void async_copy16(const void* g, void* l) {
    __builtin_amdgcn_global_load_lds((const __attribute__((address_space(1))) void*)g,
                                     (__attribute__((address_space(3))) void*)l,
                                     16, 0, 0);
}

// ---------------- x fp32 -> bf16 (vectorized) + counter reset ----------------
__global__ __launch_bounds__(256) void convert_x_kernel(const float* __restrict__ x,
                                                        __bf16* __restrict__ xb,
                                                        long total,
                                                        unsigned* __restrict__ counter) {
    if (counter && blockIdx.x == 0 && threadIdx.x == 0) counter[0] = 0u;
    long i = ((long)blockIdx.x * 256 + threadIdx.x) * 8;
    if (i >= total) return;
    const float4* p = (const float4*)(x + i);
    float4 u = p[0], v = p[1];
    bf16x8_t o;
    o[0] = (__bf16)u.x; o[1] = (__bf16)u.y; o[2] = (__bf16)u.z; o[3] = (__bf16)u.w;
    o[4] = (__bf16)v.x; o[5] = (__bf16)v.y; o[6] = (__bf16)v.z; o[7] = (__bf16)v.w;
    *(bf16x8_t*)(xb + i) = o;
}

// ---------------- GPTQ dequant -> W^T [N][K] bf16 ----------------
__global__ __launch_bounds__(256) void dequant_kernel(const int* __restrict__ qw,
                                                      const int* __restrict__ qz,
                                                      const float* __restrict__ sc,
                                                      __bf16* __restrict__ Wt) {
    __shared__ __align__(16) __bf16 dqT[128 * 136];  // [n][k] pad +8 bf16
    __shared__ float dqS[128];
    __shared__ float dqB[128];
    const int n0 = blockIdx.x * 128;
    const int g  = blockIdx.y;          // group index == k-tile (k0 = g*128)
    const int t  = threadIdx.x;

    if (t < 128) {
        int n = n0 + t;
        float s = sc[(size_t)g * N_DIM + n];
        int z = (qz[(size_t)g * (N_DIM / 8) + (n >> 3)] >> ((n & 7) * 4)) & 15;
        dqS[t] = s;
        dqB[t] = -(float)(z + 1) * s;     // GPTQ +1 zero offset
    }
    __syncthreads();

#pragma unroll
    for (int it = 0; it < 8; ++it) {
        int wi  = it * 256 + t;
        int row = wi >> 7;               // 0..15 (kp sub-row)
        int col = wi & 127;              // n sub-col
        int q = qw[(size_t)(g * 16 + row) * N_DIM + n0 + col];
        float s = dqS[col], b = dqB[col];
        bf16x8_t v;
#pragma unroll
        for (int j = 0; j < 8; ++j) {
            float w = (float)((q >> (4 * j)) & 15);
            v[j] = (__bf16)fmaf(w, s, b);
        }
        *(bf16x8_t*)(&dqT[col * 136 + row * 8]) = v;
    }
    __syncthreads();

    int n_loc = t & 127, half = t >> 7;
    const __bf16* src = &dqT[n_loc * 136 + half * 64];
    __bf16* dst = Wt + (size_t)(n0 + n_loc) * K_DIM + g * GROUP_SZ + half * 64;
#pragma unroll
    for (int i = 0; i < 8; ++i)
        *(bf16x8_t*)(dst + i * 8) = *(const bf16x8_t*)(src + i * 8);
}

__device__ __forceinline__ void map_tile(int vid, int mtiles, int ntiles,
                                         int& mt, int& nt) {
    if ((mtiles & 15) == 0) {          // band supertiling for L3 locality
        const int bandsz = 16 * ntiles;
        const int band = vid / bandsz, rem = vid % bandsz;
        nt = rem >> 4;
        mt = (band << 4) + (rem & 15);
    } else {
        mt = vid % mtiles;
        nt = vid / mtiles;
    }
}

// ---------------- 256x256 8-wave MFMA GEMM (persistent, prefetch+pin) --------
__global__ __launch_bounds__(512, 2) void gemm256_kernel(const __bf16* __restrict__ A,
                                                         const __bf16* __restrict__ Bt,
                                                         float* __restrict__ C,
                                                         int mtiles, int ntiles,
                                                         unsigned* counter, int ntotal) {
    __shared__ __align__(16) char ldsA[2][256 * 128];   // 64 KB
    __shared__ __align__(16) char ldsB[2][256 * 128];   // 64 KB
    __shared__ int sVid;
    const int tid = threadIdx.x;

    // Staging offsets. Quadrant row maps (preserve row&7 == r&7 so the XOR
    // swizzle mask matches the reader's (row&7)<<4):
    //   A-Q0: r + (r&64)   -> rows {0-63,128-191};  A-Q1 = +64
    //   B-Q0: r + (r&~31)  -> rows {0-31,64-95,128-159,192-223}; B-Q1 = +32
    // LDS dest LINEAR in lane order; inverse XOR swizzle on the GLOBAL source.
    int srcA[2], srcB[2], dstA[2], dstB[2];
#pragma unroll
    for (int q = 0; q < 2; ++q) {
        const int f = q * 512 + tid;
        const int r = f >> 3, c = f & 7;
        const int swz = (c * 16) ^ ((r & 7) << 4);
        const int Ra = r + (r & 64);
        const int Rb = r + (r & ~31);
        srcA[q] = Ra * KB + swz;  dstA[q] = Ra * 128 + c * 16;
        srcB[q] = Rb * KB + swz;  dstB[q] = Rb * 128 + c * 16;
    }

    const int lane = tid & 63;
    const int wid = tid >> 6;
    const int wm = wid >> 2, wn = wid & 3;        // 2 x 4 waves
    const int lr = lane & 15, lq = lane >> 4;
    const int kOff0 = (lq * 16) ^ ((lr & 7) << 4);
    const int kOff1 = (64 + lq * 16) ^ ((lr & 7) << 4);
    const int aRowBase = wm * 128 + lr;           // + mq*64 + i*16
    const int bRowBase = wn * 64 + lr;            // + n*16

    // Named frag sets (static indexing; single set each, lifetimes verified).
    bf16x8_t aLo[4][2], aHi[4][2], b0[2][2], b1[2][2];
    f32x4_t acc[8][4];

#define GL_A(AP, KT, BUFS, ROFF) do {                                                      \
    async_copy16((AP) + (size_t)(KT) * 128 + (ROFF) * KB + srcA[0],                        \
                 &ldsA[BUFS][(ROFF) * 128] + dstA[0]);                                     \
    async_copy16((AP) + (size_t)(KT) * 128 + (ROFF) * KB + srcA[1],                        \
                 &ldsA[BUFS][(ROFF) * 128] + dstA[1]);                                     \
} while (0)
#define GL_B(BP, KT, BUFS, ROFF) do {                                                      \
    async_copy16((BP) + (size_t)(KT) * 128 + (ROFF) * KB + srcB[0],                        \
                 &ldsB[BUFS][(ROFF) * 128] + dstB[0]);                                     \
    async_copy16((BP) + (size_t)(KT) * 128 + (ROFF) * KB + srcB[1],                        \
                 &ldsB[BUFS][(ROFF) * 128] + dstB[1]);                                     \
} while (0)
// READ_AX(DST, MQ, BUF): 8 ds_read_b128 into DST[4][2]
#define READ_AX(DST, MQ, BUF) do {                                                         \
    _Pragma("unroll") for (int i = 0; i < 4; ++i) {                                        \
        const char* _p = &ldsA[BUF][(aRowBase + (MQ) * 64 + i * 16) * 128];                \
        DST[i][0] = *(const bf16x8_t*)(_p + kOff0);                                        \
        DST[i][1] = *(const bf16x8_t*)(_p + kOff1);                                        \
    }                                                                                      \
} while (0)
// READ_BX(DST, NQ, BUF): 4 ds_read_b128 into DST[2][2]
#define READ_BX(DST, NQ, BUF) do {                                                         \
    _Pragma("unroll") for (int j = 0; j < 2; ++j) {                                        \
        const char* _p = &ldsB[BUF][(bRowBase + ((NQ) * 2 + j) * 16) * 128];               \
        DST[j][0] = *(const bf16x8_t*)(_p + kOff0);                                        \
        DST[j][1] = *(const bf16x8_t*)(_p + kOff1);                                        \
    }                                                                                      \
} while (0)
// 16 MFMA for quad (MQ,NQ) from named frag arrays; kk outer (acc spacing 8).
#define MFMA_Q(AARR, BARR, MQ, NQ) do {                                                    \
    _Pragma("unroll") for (int kk = 0; kk < 2; ++kk)                                       \
    _Pragma("unroll") for (int i = 0; i < 4; ++i)                                          \
    _Pragma("unroll") for (int j = 0; j < 2; ++j)                                          \
        acc[(MQ) * 4 + i][(NQ) * 2 + j] = __builtin_amdgcn_mfma_f32_16x16x32_bf16(         \
            AARR[i][kk], BARR[j][kk], acc[(MQ) * 4 + i][(NQ) * 2 + j], 0, 0, 0);           \
} while (0)
#define BARRIER() asm volatile("s_barrier" ::: "memory")
#define VMCNT4()  asm volatile("s_waitcnt vmcnt(4)" ::: "memory")
#define VMCNT2()  asm volatile("s_waitcnt vmcnt(2)" ::: "memory")
#define VMCNT0()  asm volatile("s_waitcnt vmcnt(0)" ::: "memory")
#define SCHED0()  __builtin_amdgcn_sched_barrier(0)

// Steady K-tile: compute kt from BUFC; stage KTS into BUFC^1.
// q1..q4 = quads (0,0),(0,1),(1,0),(1,1); prefetch next quad's frags after
// each barrier, PINNED above the MFMA cluster by sched_barrier(0).
#define KTILE(AP, BP, BUFC, KTS) do {                                                      \
    /* q1 */                                                                               \
    GL_A(AP, KTS, (BUFC) ^ 1, 0);                                                          \
    VMCNT4(); BARRIER();              /* publishes B1(t) */                                \
    READ_BX(b1, 1, BUFC);                                                                  \
    SCHED0();                                                                              \
    MFMA_Q(aLo, b0, 0, 0);                                                                 \
    /* q2 */                                                                               \
    GL_B(BP, KTS, (BUFC) ^ 1, 0);                                                          \
    VMCNT4(); BARRIER();              /* publishes A1(t) */                                \
    READ_AX(aHi, 1, BUFC);                                                                 \
    SCHED0();                                                                              \
    MFMA_Q(aLo, b1, 0, 1);                                                                 \
    /* q3: no barrier, no wait */                                                          \
    GL_B(BP, KTS, (BUFC) ^ 1, 32);                                                         \
    MFMA_Q(aHi, b0, 1, 0);                                                                 \
    /* q4 */                                                                               \
    GL_A(AP, KTS, (BUFC) ^ 1, 64);                                                         \
    VMCNT4(); BARRIER();              /* publishes A0,B0(t+1) */                           \
    READ_AX(aLo, 0, (BUFC) ^ 1);                                                           \
    READ_BX(b0, 0, (BUFC) ^ 1);                                                            \
    SCHED0();                                                                              \
    MFMA_Q(aHi, b1, 1, 1);                                                                 \
} while (0)

// Final K-tile (kt=63, buf1): stage NEXT output tile's kt0 into buf0.
// !HAVE: tighter counts (nothing new in flight); q4 prefetch reads stale
// buf0 data that is never consumed (loop exits).
#define KTILE_LAST(NAP, NBP, HAVE) do {                                                    \
    if (HAVE) { GL_A(NAP, 0, 0, 0); VMCNT4(); } else { VMCNT2(); }                         \
    BARRIER();                                                                             \
    READ_BX(b1, 1, 1);                                                                     \
    SCHED0();                                                                              \
    MFMA_Q(aLo, b0, 0, 0);                                                                 \
    if (HAVE) { GL_B(NBP, 0, 0, 0); VMCNT4(); } else { VMCNT0(); }                         \
    BARRIER();                                                                             \
    READ_AX(aHi, 1, 1);                                                                    \
    SCHED0();                                                                              \
    MFMA_Q(aLo, b1, 0, 1);                                                                 \
    if (HAVE) GL_B(NBP, 0, 0, 32);                                                         \
    MFMA_Q(aHi, b0, 1, 0);                                                                 \
    if (HAVE) { GL_A(NAP, 0, 0, 64); VMCNT4(); }                                           \
    BARRIER();                                                                             \
    READ_AX(aLo, 0, 0);                                                                    \
    READ_BX(b0, 0, 0);                                                                     \
    SCHED0();                                                                              \
    MFMA_Q(aHi, b1, 1, 1);                                                                 \
} while (0)

    // First tile grab.
    int vid;
    if (counter) {
        if (tid == 0) sVid = (int)atomicAdd(counter, 1u);
        __syncthreads();
        vid = sVid;
    } else {
        const int nwg = gridDim.x, bid = blockIdx.x;
        vid = (nwg & 7) ? bid : ((bid & 7) * (nwg >> 3) + (bid >> 3));
    }

    bool first = true;
    while (vid < ntotal) {
        int mt, nt;
        map_tile(vid, mtiles, ntiles, mt, nt);
        const char* aPanel = (const char*)A + (size_t)mt * 256 * KB;
        const char* bPanel = (const char*)Bt + (size_t)nt * 256 * KB;

        if (first) {
            // Stage kt0 (canonical A0,B0,B1,A1) -> buf0; drain A0,B0; publish;
            // prefetch aLo,b0. Leaves {B1,A1}=4 outstanding = steady state.
            GL_A(aPanel, 0, 0, 0); GL_B(bPanel, 0, 0, 0);
            GL_B(bPanel, 0, 0, 32); GL_A(aPanel, 0, 0, 64);
            VMCNT4(); BARRIER();
            READ_AX(aLo, 0, 0);
            READ_BX(b0, 0, 0);
            first = false;
        }

#pragma unroll
        for (int m = 0; m < 8; ++m)
#pragma unroll
            for (int n = 0; n < 4; ++n)
                acc[m][n] = (f32x4_t){0.f, 0.f, 0.f, 0.f};

#pragma unroll 1
        for (int kt = 0; kt < NTILES_K - 2; kt += 2) {
            KTILE(aPanel, bPanel, 0, kt + 1);
            KTILE(aPanel, bPanel, 1, kt + 2);
        }
        KTILE(aPanel, bPanel, 0, NTILES_K - 1);   // kt=62, stages kt63 -> buf1

        // Grab next tile before the final K-tile so its kt0 staging overlaps.
        int nvid;
        if (counter) {
            if (tid == 0) sVid = (int)atomicAdd(counter, 1u);
            __syncthreads();
            nvid = sVid;
        } else {
            nvid = ntotal;
        }
        const bool have = nvid < ntotal;
        const char* naP = aPanel;
        const char* nbP = bPanel;
        if (have) {
            int nmt, nnt;
            map_tile(nvid, mtiles, ntiles, nmt, nnt);
            naP = (const char*)A + (size_t)nmt * 256 * KB;
            nbP = (const char*)Bt + (size_t)nnt * 256 * KB;
        }
        KTILE_LAST(naP, nbP, have);               // kt=63, stages next kt0 -> buf0

        // Epilogue: C/D layout col=lane&15, row=(lane>>4)*4+reg.
        // Overlaps the next tile's kt0 HBM latency.
#pragma unroll
        for (int m = 0; m < 8; ++m) {
            const size_t gr = (size_t)mt * 256 + wm * 128 + m * 16 + lq * 4;
#pragma unroll
            for (int n = 0; n < 4; ++n) {
                const size_t gc = (size_t)nt * 256 + wn * 64 + n * 16 + lr;
                float* cp = C + gr * N_DIM + gc;
#pragma unroll
                for (int rg = 0; rg < 4; ++rg)
                    cp[(size_t)rg * N_DIM] = acc[m][n][rg];
            }
        }

        vid = nvid;
    }
}

// ---------------- fallback (ws too small / odd shape): fused fp32 ----------------
__global__ __launch_bounds__(256) void fallback_kernel(const float* __restrict__ x,
                                                       const int* __restrict__ qw,
                                                       const int* __restrict__ qz,
                                                       const float* __restrict__ sc,
                                                       float* __restrict__ out) {
    __shared__ float xrow[K_DIM];
    const int t = blockIdx.y;
    const int n = blockIdx.x * 256 + threadIdx.x;
    for (int i = threadIdx.x; i < K_DIM; i += 256)
        xrow[i] = x[(size_t)t * K_DIM + i];
    __syncthreads();
    if (n >= N_DIM) return;
    float acc = 0.f;
    for (int g = 0; g < K_DIM / GROUP_SZ; ++g) {
        float s = sc[(size_t)g * N_DIM + n];
        int z = (qz[(size_t)g * (N_DIM / 8) + (n >> 3)] >> ((n & 7) * 4)) & 15;
        float b = -(float)(z + 1) * s;
        for (int kp = g * 16; kp < g * 16 + 16; ++kp) {
            int q = qw[(size_t)kp * N_DIM + n];
#pragma unroll
            for (int j = 0; j < 8; ++j) {
                float w = (float)((q >> (4 * j)) & 15);
                acc = fmaf(xrow[kp * 8 + j], fmaf(w, s, b), acc);
            }
        }
    }
    out[(size_t)t * N_DIM + n] = acc;
}

extern "C" void kernel_launch(void* const* d_in, const int* in_sizes, int n_in,
                              void* d_out, int out_size, void* d_ws, size_t ws_size,
                              hipStream_t stream) {
    const float* x  = (const float*)d_in[0];
    const int*   qw = (const int*)d_in[1];
    const int*   qz = (const int*)d_in[2];
    const float* sc = (const float*)d_in[3];
    float* out = (float*)d_out;

    const long T = (long)in_sizes[0] / K_DIM;   // 8192
    const size_t xb_bytes = (size_t)T * K_DIM * sizeof(__bf16);
    const size_t wt_bytes = (size_t)N_DIM * K_DIM * sizeof(__bf16);
    const size_t cnt_off  = (xb_bytes + wt_bytes + 255) & ~(size_t)255;

    if (ws_size >= xb_bytes + wt_bytes && (T % 256) == 0) {
        __bf16* xb = (__bf16*)d_ws;
        __bf16* Wt = (__bf16*)((char*)d_ws + xb_bytes);
        unsigned* counter = (ws_size >= cnt_off + 256)
                          ? (unsigned*)((char*)d_ws + cnt_off) : nullptr;
        long total = T * K_DIM;
        long nthr = total / 8;
        convert_x_kernel<<<dim3((unsigned)((nthr + 255) / 256)), dim3(256), 0, stream>>>(x, xb, total, counter);
        dequant_kernel<<<dim3(N_DIM / 128, K_DIM / GROUP_SZ), dim3(256), 0, stream>>>(qw, qz, sc, Wt);
        const int mtiles = (int)(T / 256);          // 32
        const int ntiles = N_DIM / 256;             // 43
        const int ntotal = mtiles * ntiles;         // 1376
        const unsigned grid = counter ? 256u : (unsigned)ntotal;
        gemm256_kernel<<<dim3(grid), dim3(512), 0, stream>>>(xb, Wt, out, mtiles, ntiles, counter, ntotal);
    } else {
        fallback_kernel<<<dim3(N_DIM / 256 + 1, (unsigned)T), dim3(256), 0, stream>>>(x, qw, qz, sc, out);
    }
}

// Round 16
// 650.189 us; speedup vs baseline: 2.1289x; 2.1289x over previous
//
#include <hip/hip_runtime.h>
#include <hip/hip_bf16.h>
#include <cstdint>
#include <cstddef>

// GPTQ int4 linear: out[T,N] = x[T,K] @ dequant(qweight,qzeros,scales)
// T=8192, K=4096, N=11008, GROUP=128.
// Pipeline: x->bf16, dequant->W^T[N,K] bf16, then 256x256-tile 8-wave MFMA GEMM
// (persistent, atomic tile grab).
// R16 = R14 (best verified: total 729us, GEMM ~665us, MfmaUtil 51%)
//       + __builtin_nontemporal_store for the C epilogue (C is write-once,
//       never re-read; NT stores stop evicting A/B panels from per-XCD L2).
// R14's structure: 4 phases/K-tile, barriers at ph0/ph1/ph3 each paired with
// counted vmcnt(4); ph2 has neither. FIFO ledger (2 loads/GL, stage order
// A0',B0',B1',A1' at ph0..ph3; steady queue at ph0 entry = {b1_t, a1_t}):
//   ph0: +a0' -> 6; vmcnt(4) drains b1_t  -> ph1's READ_B(1) safe after bar
//   ph1: +b0' -> 6; vmcnt(4) drains a1_t  -> ph2's READ_A(1) safe after bar
//   ph2: +b1' -> 6; (no wait/barrier: ph3 reads nothing; WAR covered)
//   ph3: +a1' -> 8; vmcnt(4) drains a0',b0' -> next ph0's reads safe after bar
// Every wait targets loads issued >=2 phases back; never drains to 0.
// Session A/B ledger: setprio neutral (R8), ph2-barrier removal neutral (R14),
// prefetch -/-- (R12/R13/R15), m201 2-bar port - (R7), 32x32 MFMA - (R4,
// 4-way bank conflict), 1-bar-per-tile counted vmcnt broken (R10/R11:
// vmcnt is wave-local; cross-wave publication needs the paired barrier).

#define K_DIM 4096
#define N_DIM 11008
#define GROUP_SZ 128
#define KB (K_DIM * 2)        // bytes per row of a K-major bf16 panel
#define NTILES_K (K_DIM / 64) // 64 K-tiles of BK=64

typedef __bf16 bf16x8_t __attribute__((ext_vector_type(8)));
typedef float f32x4_t __attribute__((ext_vector_type(4)));

__device__ __forceinline__ void async_copy16(const void* g, void* l) {
    __builtin_amdgcn_global_load_lds((const __attribute__((address_space(1))) void*)g,
                                     (__attribute__((address_space(3))) void*)l,
                                     16, 0, 0);
}

// ---------------- x fp32 -> bf16 (vectorized) + counter reset ----------------
__global__ __launch_bounds__(256) void convert_x_kernel(const float* __restrict__ x,
                                                        __bf16* __restrict__ xb,
                                                        long total,
                                                        unsigned* __restrict__ counter) {
    if (counter && blockIdx.x == 0 && threadIdx.x == 0) counter[0] = 0u;
    long i = ((long)blockIdx.x * 256 + threadIdx.x) * 8;
    if (i >= total) return;
    const float4* p = (const float4*)(x + i);
    float4 u = p[0], v = p[1];
    bf16x8_t o;
    o[0] = (__bf16)u.x; o[1] = (__bf16)u.y; o[2] = (__bf16)u.z; o[3] = (__bf16)u.w;
    o[4] = (__bf16)v.x; o[5] = (__bf16)v.y; o[6] = (__bf16)v.z; o[7] = (__bf16)v.w;
    *(bf16x8_t*)(xb + i) = o;
}

// ---------------- GPTQ dequant -> W^T [N][K] bf16 ----------------
__global__ __launch_bounds__(256) void dequant_kernel(const int* __restrict__ qw,
                                                      const int* __restrict__ qz,
                                                      const float* __restrict__ sc,
                                                      __bf16* __restrict__ Wt) {
    __shared__ __align__(16) __bf16 dqT[128 * 136];  // [n][k] pad +8 bf16
    __shared__ float dqS[128];
    __shared__ float dqB[128];
    const int n0 = blockIdx.x * 128;
    const int g  = blockIdx.y;          // group index == k-tile (k0 = g*128)
    const int t  = threadIdx.x;

    if (t < 128) {
        int n = n0 + t;
        float s = sc[(size_t)g * N_DIM + n];
        int z = (qz[(size_t)g * (N_DIM / 8) + (n >> 3)] >> ((n & 7) * 4)) & 15;
        dqS[t] = s;
        dqB[t] = -(float)(z + 1) * s;     // GPTQ +1 zero offset
    }
    __syncthreads();

#pragma unroll
    for (int it = 0; it < 8; ++it) {
        int wi  = it * 256 + t;
        int row = wi >> 7;               // 0..15 (kp sub-row)
        int col = wi & 127;              // n sub-col
        int q = qw[(size_t)(g * 16 + row) * N_DIM + n0 + col];
        float s = dqS[col], b = dqB[col];
        bf16x8_t v;
#pragma unroll
        for (int j = 0; j < 8; ++j) {
            float w = (float)((q >> (4 * j)) & 15);
            v[j] = (__bf16)fmaf(w, s, b);
        }
        *(bf16x8_t*)(&dqT[col * 136 + row * 8]) = v;
    }
    __syncthreads();

    int n_loc = t & 127, half = t >> 7;
    const __bf16* src = &dqT[n_loc * 136 + half * 64];
    __bf16* dst = Wt + (size_t)(n0 + n_loc) * K_DIM + g * GROUP_SZ + half * 64;
#pragma unroll
    for (int i = 0; i < 8; ++i)
        *(bf16x8_t*)(dst + i * 8) = *(const bf16x8_t*)(src + i * 8);
}

__device__ __forceinline__ void map_tile(int vid, int mtiles, int ntiles,
                                         int& mt, int& nt) {
    if ((mtiles & 15) == 0) {          // band supertiling for L3 locality
        const int bandsz = 16 * ntiles;
        const int band = vid / bandsz, rem = vid % bandsz;
        nt = rem >> 4;
        mt = (band << 4) + (rem & 15);
    } else {
        mt = vid % mtiles;
        nt = vid / mtiles;
    }
}

// ---------------- 256x256 8-wave 4-phase MFMA GEMM (persistent) ----------------
__global__ __launch_bounds__(512, 2) void gemm256_kernel(const __bf16* __restrict__ A,
                                                         const __bf16* __restrict__ Bt,
                                                         float* __restrict__ C,
                                                         int mtiles, int ntiles,
                                                         unsigned* counter, int ntotal) {
    __shared__ __align__(16) char ldsA[2][256 * 128];   // 64 KB
    __shared__ __align__(16) char ldsB[2][256 * 128];   // 64 KB
    __shared__ int sVid;
    const int tid = threadIdx.x;

    // Staging offsets. Quadrant row maps (preserve row&7 == r&7 so the XOR
    // swizzle mask matches the reader's (row&7)<<4):
    //   A-Q0: r + (r&64)   -> rows {0-63,128-191};  A-Q1 = +64
    //   B-Q0: r + (r&~31)  -> rows {0-31,64-95,128-159,192-223}; B-Q1 = +32
    // LDS dest is LINEAR in lane order (global_load_lds constraint); the
    // inverse XOR swizzle is applied to the GLOBAL source (both-sides rule).
    int srcA[2], srcB[2], dstA[2], dstB[2];
#pragma unroll
    for (int q = 0; q < 2; ++q) {
        const int f = q * 512 + tid;
        const int r = f >> 3, c = f & 7;
        const int swz = (c * 16) ^ ((r & 7) << 4);
        const int Ra = r + (r & 64);
        const int Rb = r + (r & ~31);
        srcA[q] = Ra * KB + swz;  dstA[q] = Ra * 128 + c * 16;
        srcB[q] = Rb * KB + swz;  dstB[q] = Rb * 128 + c * 16;
    }

    const int lane = tid & 63;
    const int wid = tid >> 6;
    const int wm = wid >> 2, wn = wid & 3;        // 2 x 4 waves
    const int lr = lane & 15, lq = lane >> 4;
    const int kOff0 = (lq * 16) ^ ((lr & 7) << 4);
    const int kOff1 = (64 + lq * 16) ^ ((lr & 7) << 4);
    const int aRowBase = wm * 128 + lr;           // + mq*64 + i*16
    const int bRowBase = wn * 64 + lr;            // + n*16

    bf16x8_t aF[4][2], bF[4][2];
    f32x4_t acc[8][4];

#define GL_A(AP, KT, BUFS, ROFF) do {                                                      \
    async_copy16((AP) + (size_t)(KT) * 128 + (ROFF) * KB + srcA[0],                        \
                 &ldsA[BUFS][(ROFF) * 128] + dstA[0]);                                     \
    async_copy16((AP) + (size_t)(KT) * 128 + (ROFF) * KB + srcA[1],                        \
                 &ldsA[BUFS][(ROFF) * 128] + dstA[1]);                                     \
} while (0)
#define GL_B(BP, KT, BUFS, ROFF) do {                                                      \
    async_copy16((BP) + (size_t)(KT) * 128 + (ROFF) * KB + srcB[0],                        \
                 &ldsB[BUFS][(ROFF) * 128] + dstB[0]);                                     \
    async_copy16((BP) + (size_t)(KT) * 128 + (ROFF) * KB + srcB[1],                        \
                 &ldsB[BUFS][(ROFF) * 128] + dstB[1]);                                     \
} while (0)
#define READ_A(MQ, BUFC) do {                                                              \
    _Pragma("unroll") for (int i = 0; i < 4; ++i) {                                        \
        const char* _p = &ldsA[BUFC][(aRowBase + (MQ) * 64 + i * 16) * 128];               \
        aF[i][0] = *(const bf16x8_t*)(_p + kOff0);                                         \
        aF[i][1] = *(const bf16x8_t*)(_p + kOff1);                                         \
    }                                                                                      \
} while (0)
#define READ_B(NQ, BUFC) do {                                                              \
    _Pragma("unroll") for (int j = 0; j < 2; ++j) {                                        \
        const char* _p = &ldsB[BUFC][(bRowBase + ((NQ) * 2 + j) * 16) * 128];              \
        bF[(NQ) * 2 + j][0] = *(const bf16x8_t*)(_p + kOff0);                              \
        bF[(NQ) * 2 + j][1] = *(const bf16x8_t*)(_p + kOff1);                              \
    }                                                                                      \
} while (0)
#define MFMA_QUAD(MQ, NQ) do {                                                             \
    _Pragma("unroll") for (int kk = 0; kk < 2; ++kk)                                       \
    _Pragma("unroll") for (int i = 0; i < 4; ++i)                                          \
    _Pragma("unroll") for (int j = 0; j < 2; ++j)                                          \
        acc[(MQ) * 4 + i][(NQ) * 2 + j] = __builtin_amdgcn_mfma_f32_16x16x32_bf16(         \
            aF[i][kk], bF[(NQ) * 2 + j][kk], acc[(MQ) * 4 + i][(NQ) * 2 + j], 0, 0, 0);    \
} while (0)
#define BARRIER() asm volatile("s_barrier" ::: "memory")
#define VMCNT4()  asm volatile("s_waitcnt vmcnt(4)" ::: "memory")
#define VMCNT0()  asm volatile("s_waitcnt vmcnt(0)" ::: "memory")

// Steady K-tile: compute from BUFC, stage K-tile KTS quadrants into BUFC^1.
#define KTILE(AP, BP, BUFC, KTS) do {                                                      \
    READ_A(0, BUFC); READ_B(0, BUFC);                                                      \
    GL_A(AP, KTS, (BUFC) ^ 1, 0);                                                          \
    VMCNT4(); BARRIER();                                                                   \
    MFMA_QUAD(0, 0);                                                                       \
    READ_B(1, BUFC);                                                                       \
    GL_B(BP, KTS, (BUFC) ^ 1, 0);                                                          \
    VMCNT4(); BARRIER();                                                                   \
    MFMA_QUAD(0, 1);                                                                       \
    READ_A(1, BUFC);                                                                       \
    GL_B(BP, KTS, (BUFC) ^ 1, 32);                                                         \
    MFMA_QUAD(1, 1);          /* ph2: no wait, no barrier */                               \
    GL_A(AP, KTS, (BUFC) ^ 1, 64);                                                         \
    VMCNT4(); BARRIER();                                                                   \
    MFMA_QUAD(1, 0);                                                                       \
} while (0)

// Final K-tile (kt=63, buf1): stage NEXT output tile's kt0 into buf0.
// If !HAVE, drain at ph0 (vmcnt(0)); later vmcnt(4)s become no-ops.
#define KTILE_LAST(NAP, NBP, HAVE) do {                                                    \
    READ_A(0, 1); READ_B(0, 1);                                                            \
    if (HAVE) { GL_A(NAP, 0, 0, 0); VMCNT4(); } else { VMCNT0(); }                         \
    BARRIER();                                                                             \
    MFMA_QUAD(0, 0);                                                                       \
    READ_B(1, 1);                                                                          \
    if (HAVE) GL_B(NBP, 0, 0, 0);                                                          \
    VMCNT4(); BARRIER();                                                                   \
    MFMA_QUAD(0, 1);                                                                       \
    READ_A(1, 1);                                                                          \
    if (HAVE) GL_B(NBP, 0, 0, 32);                                                         \
    MFMA_QUAD(1, 1);          /* ph2: no barrier */                                        \
    if (HAVE) GL_A(NAP, 0, 0, 64);                                                         \
    VMCNT4(); BARRIER();                                                                   \
    MFMA_QUAD(1, 0);                                                                       \
} while (0)

    // First tile grab.
    int vid;
    if (counter) {
        if (tid == 0) sVid = (int)atomicAdd(counter, 1u);
        __syncthreads();
        vid = sVid;
    } else {
        const int nwg = gridDim.x, bid = blockIdx.x;
        vid = (nwg & 7) ? bid : ((bid & 7) * (nwg >> 3) + (bid >> 3));
    }

    bool first = true;
    while (vid < ntotal) {
        int mt, nt;
        map_tile(vid, mtiles, ntiles, mt, nt);
        const char* aPanel = (const char*)A + (size_t)mt * 256 * KB;
        const char* bPanel = (const char*)Bt + (size_t)nt * 256 * KB;

        if (first) {   // stage kt0 quadrants -> buf0 (else staged by prev KTILE_LAST)
            GL_A(aPanel, 0, 0, 0); GL_B(bPanel, 0, 0, 0);
            GL_B(bPanel, 0, 0, 32); GL_A(aPanel, 0, 0, 64);
            VMCNT4(); BARRIER();
            first = false;
        }

#pragma unroll
        for (int m = 0; m < 8; ++m)
#pragma unroll
            for (int n = 0; n < 4; ++n)
                acc[m][n] = (f32x4_t){0.f, 0.f, 0.f, 0.f};

#pragma unroll 1
        for (int kt = 0; kt < NTILES_K - 2; kt += 2) {
            KTILE(aPanel, bPanel, 0, kt + 1);
            KTILE(aPanel, bPanel, 1, kt + 2);
        }
        KTILE(aPanel, bPanel, 0, NTILES_K - 1);   // kt=62, stages kt63 -> buf1

        // Grab next tile before the final K-tile so its kt0 staging overlaps.
        int nvid;
        if (counter) {
            if (tid == 0) sVid = (int)atomicAdd(counter, 1u);
            __syncthreads();
            nvid = sVid;
        } else {
            nvid = ntotal;
        }
        const bool have = nvid < ntotal;
        const char* naP = aPanel;
        const char* nbP = bPanel;
        if (have) {
            int nmt, nnt;
            map_tile(nvid, mtiles, ntiles, nmt, nnt);
            naP = (const char*)A + (size_t)nmt * 256 * KB;
            nbP = (const char*)Bt + (size_t)nnt * 256 * KB;
        }
        KTILE_LAST(naP, nbP, have);               // kt=63, stages next kt0 -> buf0

        // Epilogue: C/D layout col=lane&15, row=(lane>>4)*4+reg.
        // Non-temporal stores: C is write-once, never re-read -> don't evict
        // A/B panels from L2. Overlaps the next tile's kt0 HBM latency.
#pragma unroll
        for (int m = 0; m < 8; ++m) {
            const size_t gr = (size_t)mt * 256 + wm * 128 + m * 16 + lq * 4;
#pragma unroll
            for (int n = 0; n < 4; ++n) {
                const size_t gc = (size_t)nt * 256 + wn * 64 + n * 16 + lr;
                float* cp = C + gr * N_DIM + gc;
#pragma unroll
                for (int rg = 0; rg < 4; ++rg)
                    __builtin_nontemporal_store(acc[m][n][rg], cp + (size_t)rg * N_DIM);
            }
        }

        vid = nvid;
    }
}

// ---------------- fallback (ws too small / odd shape): fused fp32 ----------------
__global__ __launch_bounds__(256) void fallback_kernel(const float* __restrict__ x,
                                                       const int* __restrict__ qw,
                                                       const int* __restrict__ qz,
                                                       const float* __restrict__ sc,
                                                       float* __restrict__ out) {
    __shared__ float xrow[K_DIM];
    const int t = blockIdx.y;
    const int n = blockIdx.x * 256 + threadIdx.x;
    for (int i = threadIdx.x; i < K_DIM; i += 256)
        xrow[i] = x[(size_t)t * K_DIM + i];
    __syncthreads();
    if (n >= N_DIM) return;
    float acc = 0.f;
    for (int g = 0; g < K_DIM / GROUP_SZ; ++g) {
        float s = sc[(size_t)g * N_DIM + n];
        int z = (qz[(size_t)g * (N_DIM / 8) + (n >> 3)] >> ((n & 7) * 4)) & 15;
        float b = -(float)(z + 1) * s;
        for (int kp = g * 16; kp < g * 16 + 16; ++kp) {
            int q = qw[(size_t)kp * N_DIM + n];
#pragma unroll
            for (int j = 0; j < 8; ++j) {
                float w = (float)((q >> (4 * j)) & 15);
                acc = fmaf(xrow[kp * 8 + j], fmaf(w, s, b), acc);
            }
        }
    }
    out[(size_t)t * N_DIM + n] = acc;
}

extern "C" void kernel_launch(void* const* d_in, const int* in_sizes, int n_in,
                              void* d_out, int out_size, void* d_ws, size_t ws_size,
                              hipStream_t stream) {
    const float* x  = (const float*)d_in[0];
    const int*   qw = (const int*)d_in[1];
    const int*   qz = (const int*)d_in[2];
    const float* sc = (const float*)d_in[3];
    float* out = (float*)d_out;

    const long T = (long)in_sizes[0] / K_DIM;   // 8192
    const size_t xb_bytes = (size_t)T * K_DIM * sizeof(__bf16);
    const size_t wt_bytes = (size_t)N_DIM * K_DIM * sizeof(__bf16);
    const size_t cnt_off  = (xb_bytes + wt_bytes + 255) & ~(size_t)255;

    if (ws_size >= xb_bytes + wt_bytes && (T % 256) == 0) {
        __bf16* xb = (__bf16*)d_ws;
        __bf16* Wt = (__bf16*)((char*)d_ws + xb_bytes);
        unsigned* counter = (ws_size >= cnt_off + 256)
                          ? (unsigned*)((char*)d_ws + cnt_off) : nullptr;
        long total = T * K_DIM;
        long nthr = total / 8;
        convert_x_kernel<<<dim3((unsigned)((nthr + 255) / 256)), dim3(256), 0, stream>>>(x, xb, total, counter);
        dequant_kernel<<<dim3(N_DIM / 128, K_DIM / GROUP_SZ), dim3(256), 0, stream>>>(qw, qz, sc, Wt);
        const int mtiles = (int)(T / 256);          // 32
        const int ntiles = N_DIM / 256;             // 43
        const int ntotal = mtiles * ntiles;         // 1376
        const unsigned grid = counter ? 256u : (unsigned)ntotal;
        gemm256_kernel<<<dim3(grid), dim3(512), 0, stream>>>(xb, Wt, out, mtiles, ntiles, counter, ntotal);
    } else {
        fallback_kernel<<<dim3(N_DIM / 256 + 1, (unsigned)T), dim3(256), 0, stream>>>(x, qw, qz, sc, out);
    }
}